// Round 1
// baseline (858.615 us; speedup 1.0000x reference)
//
#include <hip/hip_runtime.h>
#include <hip/hip_bf16.h>
#include <math.h>

// Problem constants (from reference)
#define HSZ 1024
#define NHD 16
#define HDM 64      // head dim
#define BSZ 2
#define SEQ 2048
#define MTOT (BSZ*SEQ)   // 4096

// ---------------------------------------------------------------------------
// Kernel 1: fused QKV projection.
// q/k/v[n] = hidden @ W{q,k,v}^T + b  -> stored as [B][NH][S][HD] fp32 in ws.
// GEMM: A = hidden [4096 x 1024], B = W [1024 x 1024] (row-major, K-contig,
// i.e. C = A @ B^T). Tiles: BM=128, BN=128, BK=16; 256 threads; 8x8 micro.
// ---------------------------------------------------------------------------
__global__ __launch_bounds__(256) void qkv_proj(
    const float* __restrict__ hid,
    const float* __restrict__ Wq, const float* __restrict__ bq,
    const float* __restrict__ Wk, const float* __restrict__ bk,
    const float* __restrict__ Wv, const float* __restrict__ bv,
    float* __restrict__ qo, float* __restrict__ ko, float* __restrict__ vo)
{
    __shared__ float As[16][132];   // [k][m], pad to 132 (16B-aligned rows)
    __shared__ float Bs[16][132];   // [k][n]

    const int t  = threadIdx.x;
    const int bn = blockIdx.x;      // 0..23 : 24 tiles over N=3072 (q|k|v)
    const int bm = blockIdx.y;      // 0..31 : 32 tiles over M=4096

    const int which = bn >> 3;              // 0:q 1:k 2:v
    const int n0    = (bn & 7) << 7;        // col offset within [0,1024)
    const float* W   = (which == 0) ? Wq : (which == 1) ? Wk : Wv;
    const float* bb  = (which == 0) ? bq : (which == 1) ? bk : bv;
    float*       out = (which == 0) ? qo : (which == 1) ? ko : vo;
    const int m0 = bm << 7;

    const int lr = t >> 4;      // 0..15 row group for loads
    const int lk = t & 15;      // k index within BK tile

    float acc[8][8];
    #pragma unroll
    for (int i = 0; i < 8; ++i)
        #pragma unroll
        for (int j = 0; j < 8; ++j) acc[i][j] = 0.f;

    const int tr = t >> 4;      // micro-tile row group (8 rows)
    const int tc = t & 15;      // micro-tile col group (8 cols)

    for (int k0 = 0; k0 < 1024; k0 += 16) {
        // Stage A and B tiles (transposed to [k][m]/[k][n]) — 8 elems each
        #pragma unroll
        for (int p = 0; p < 8; ++p) {
            const int row = lr + p * 16;
            As[lk][row] = hid[(m0 + row) * 1024 + k0 + lk];
            Bs[lk][row] = W[(n0 + row) * 1024 + k0 + lk];
        }
        __syncthreads();
        #pragma unroll
        for (int kk = 0; kk < 16; ++kk) {
            const float4 a0 = *(const float4*)&As[kk][tr * 8];
            const float4 a1 = *(const float4*)&As[kk][tr * 8 + 4];
            const float4 b0 = *(const float4*)&Bs[kk][tc * 8];
            const float4 b1 = *(const float4*)&Bs[kk][tc * 8 + 4];
            const float a[8] = {a0.x,a0.y,a0.z,a0.w,a1.x,a1.y,a1.z,a1.w};
            const float b[8] = {b0.x,b0.y,b0.z,b0.w,b1.x,b1.y,b1.z,b1.w};
            #pragma unroll
            for (int i = 0; i < 8; ++i)
                #pragma unroll
                for (int j = 0; j < 8; ++j)
                    acc[i][j] = fmaf(a[i], b[j], acc[i][j]);
        }
        __syncthreads();
    }

    // Epilogue: add bias, scatter into [B][NH][S][HD]
    const int ncol0 = n0 + tc * 8;          // global col within [0,1024)
    const int hh    = ncol0 >> 6;
    const int hd0   = ncol0 & 63;           // 8-wide chunk stays in one head
    float bias[8];
    #pragma unroll
    for (int j = 0; j < 8; ++j) bias[j] = bb[ncol0 + j];

    #pragma unroll
    for (int i = 0; i < 8; ++i) {
        const int m  = m0 + tr * 8 + i;
        const int b_ = m >> 11;             // /2048
        const int s_ = m & 2047;
        float* op = out + ((((b_ * NHD + hh) * SEQ) + s_) << 6) + hd0;
        float4 o0 = {acc[i][0] + bias[0], acc[i][1] + bias[1],
                     acc[i][2] + bias[2], acc[i][3] + bias[3]};
        float4 o1 = {acc[i][4] + bias[4], acc[i][5] + bias[5],
                     acc[i][6] + bias[6], acc[i][7] + bias[7]};
        *(float4*)op       = o0;
        *(float4*)(op + 4) = o1;
    }
}

// ---------------------------------------------------------------------------
// Kernel 2: flash attention, fp32.
// Block = (q-tile 64 rows) x (head) x (batch); 256 threads; KV tiles of 64.
// Online softmax: 4 lanes per row (shfl_xor reduce), never materialize SxS.
// ---------------------------------------------------------------------------
__global__ __launch_bounds__(256) void flash_attn(
    const float* __restrict__ qg, const float* __restrict__ kg,
    const float* __restrict__ vg, const float* __restrict__ mask,
    float* __restrict__ out)
{
    __shared__ float QsT[64][68];   // [d][r]  (transposed, pre-scaled)
    __shared__ float KsT[64][68];   // [d][c]  (transposed)
    __shared__ float Vs[64][68];    // [c][d]
    __shared__ float Ps[64][68];    // [r][c]  scores -> probs
    __shared__ float mrow[64], lrow[64], crow[64];

    const int t  = threadIdx.x;
    const int qt = blockIdx.x;      // 0..31
    const int h  = blockIdx.y;      // 0..15
    const int b  = blockIdx.z;      // 0..1

    const float* qp = qg + (((b * NHD + h) * SEQ) + qt * 64) * 64;
    const float* kp = kg + ((b * NHD + h) * SEQ) * 64;
    const float* vp = vg + ((b * NHD + h) * SEQ) * 64;
    const float* mp = mask + b * SEQ;

    const int tr  = t >> 4;         // micro row group (4 rows)
    const int tc  = t & 15;         // micro col group (4 cols)
    const int lr  = t >> 4;         // load row (0..15)
    const int lc4 = (t & 15) * 4;   // load col*4

    // Q tile -> LDS transposed, scaled by 1/sqrt(64)
    #pragma unroll
    for (int p = 0; p < 4; ++p) {
        const int r = lr + p * 16;
        const float4 qv = *(const float4*)&qp[r * 64 + lc4];
        QsT[lc4 + 0][r] = qv.x * 0.125f;
        QsT[lc4 + 1][r] = qv.y * 0.125f;
        QsT[lc4 + 2][r] = qv.z * 0.125f;
        QsT[lc4 + 3][r] = qv.w * 0.125f;
    }
    if (t < 64) { mrow[t] = -INFINITY; lrow[t] = 0.f; }

    float acc[4][4];
    #pragma unroll
    for (int i = 0; i < 4; ++i)
        #pragma unroll
        for (int j = 0; j < 4; ++j) acc[i][j] = 0.f;

    for (int kt = 0; kt < 32; ++kt) {
        __syncthreads();   // protect LDS from previous iteration's readers
        // Stage K (transposed) and V tiles
        #pragma unroll
        for (int p = 0; p < 4; ++p) {
            const int r = lr + p * 16;     // k index within tile
            const float4 kv = *(const float4*)&kp[(kt * 64 + r) * 64 + lc4];
            KsT[lc4 + 0][r] = kv.x;
            KsT[lc4 + 1][r] = kv.y;
            KsT[lc4 + 2][r] = kv.z;
            KsT[lc4 + 3][r] = kv.w;
            const float4 vv = *(const float4*)&vp[(kt * 64 + r) * 64 + lc4];
            *(float4*)&Vs[r][lc4] = vv;
        }
        __syncthreads();

        // S = (Q/8) K^T  (4x4 per thread)
        float s[4][4];
        #pragma unroll
        for (int i = 0; i < 4; ++i)
            #pragma unroll
            for (int j = 0; j < 4; ++j) s[i][j] = 0.f;
        #pragma unroll
        for (int d = 0; d < 64; ++d) {
            const float4 qa = *(const float4*)&QsT[d][tr * 4];
            const float4 ka = *(const float4*)&KsT[d][tc * 4];
            const float aq[4] = {qa.x, qa.y, qa.z, qa.w};
            const float bk2[4] = {ka.x, ka.y, ka.z, ka.w};
            #pragma unroll
            for (int i = 0; i < 4; ++i)
                #pragma unroll
                for (int j = 0; j < 4; ++j)
                    s[i][j] = fmaf(aq[i], bk2[j], s[i][j]);
        }
        // additive mask, store raw scores
        const float4 mv = *(const float4*)&mp[kt * 64 + tc * 4];
        #pragma unroll
        for (int i = 0; i < 4; ++i) {
            float4 sv = {s[i][0] + mv.x, s[i][1] + mv.y,
                         s[i][2] + mv.z, s[i][3] + mv.w};
            *(float4*)&Ps[tr * 4 + i][tc * 4] = sv;
        }
        __syncthreads();

        // Online softmax: thread t -> row t>>2, quarter t&3 (16 cols each)
        {
            const int row = t >> 2, qd = t & 3;
            float* prow = &Ps[row][qd * 16];
            float4 p0 = *(float4*)&prow[0];
            float4 p1 = *(float4*)&prow[4];
            float4 p2 = *(float4*)&prow[8];
            float4 p3 = *(float4*)&prow[12];
            float pmax = fmaxf(fmaxf(fmaxf(p0.x, p0.y), fmaxf(p0.z, p0.w)),
                               fmaxf(fmaxf(p1.x, p1.y), fmaxf(p1.z, p1.w)));
            pmax = fmaxf(pmax,
                   fmaxf(fmaxf(fmaxf(p2.x, p2.y), fmaxf(p2.z, p2.w)),
                         fmaxf(fmaxf(p3.x, p3.y), fmaxf(p3.z, p3.w))));
            pmax = fmaxf(pmax, __shfl_xor(pmax, 1));
            pmax = fmaxf(pmax, __shfl_xor(pmax, 2));
            const float mold = mrow[row];
            const float mnew = fmaxf(fmaxf(mold, pmax), -1e30f);
            const float corr = __expf(mold - mnew);
            p0.x = __expf(p0.x - mnew); p0.y = __expf(p0.y - mnew);
            p0.z = __expf(p0.z - mnew); p0.w = __expf(p0.w - mnew);
            p1.x = __expf(p1.x - mnew); p1.y = __expf(p1.y - mnew);
            p1.z = __expf(p1.z - mnew); p1.w = __expf(p1.w - mnew);
            p2.x = __expf(p2.x - mnew); p2.y = __expf(p2.y - mnew);
            p2.z = __expf(p2.z - mnew); p2.w = __expf(p2.w - mnew);
            p3.x = __expf(p3.x - mnew); p3.y = __expf(p3.y - mnew);
            p3.z = __expf(p3.z - mnew); p3.w = __expf(p3.w - mnew);
            float psum = (p0.x + p0.y + p0.z + p0.w) + (p1.x + p1.y + p1.z + p1.w)
                       + (p2.x + p2.y + p2.z + p2.w) + (p3.x + p3.y + p3.z + p3.w);
            *(float4*)&prow[0]  = p0;
            *(float4*)&prow[4]  = p1;
            *(float4*)&prow[8]  = p2;
            *(float4*)&prow[12] = p3;
            psum += __shfl_xor(psum, 1);
            psum += __shfl_xor(psum, 2);
            if (qd == 0) {
                mrow[row] = mnew;
                lrow[row] = lrow[row] * corr + psum;
                crow[row] = corr;
            }
        }
        __syncthreads();

        // Rescale accumulator, then O += P @ V
        {
            const float c0 = crow[tr * 4 + 0];
            const float c1 = crow[tr * 4 + 1];
            const float c2 = crow[tr * 4 + 2];
            const float c3 = crow[tr * 4 + 3];
            #pragma unroll
            for (int j = 0; j < 4; ++j) {
                acc[0][j] *= c0; acc[1][j] *= c1;
                acc[2][j] *= c2; acc[3][j] *= c3;
            }
        }
        #pragma unroll
        for (int c0i = 0; c0i < 16; ++c0i) {
            const float4 pa0 = *(const float4*)&Ps[tr * 4 + 0][c0i * 4];
            const float4 pa1 = *(const float4*)&Ps[tr * 4 + 1][c0i * 4];
            const float4 pa2 = *(const float4*)&Ps[tr * 4 + 2][c0i * 4];
            const float4 pa3 = *(const float4*)&Ps[tr * 4 + 3][c0i * 4];
            const float pa[4][4] = {{pa0.x,pa0.y,pa0.z,pa0.w},
                                    {pa1.x,pa1.y,pa1.z,pa1.w},
                                    {pa2.x,pa2.y,pa2.z,pa2.w},
                                    {pa3.x,pa3.y,pa3.z,pa3.w}};
            #pragma unroll
            for (int cj = 0; cj < 4; ++cj) {
                const float4 vb = *(const float4*)&Vs[c0i * 4 + cj][tc * 4];
                const float vbv[4] = {vb.x, vb.y, vb.z, vb.w};
                #pragma unroll
                for (int i = 0; i < 4; ++i)
                    #pragma unroll
                    for (int j = 0; j < 4; ++j)
                        acc[i][j] = fmaf(pa[i][cj], vbv[j], acc[i][j]);
            }
        }
    }

    // Epilogue: O /= l, write [B][S][H] (merge heads)
    #pragma unroll
    for (int i = 0; i < 4; ++i) {
        const float linv = 1.f / lrow[tr * 4 + i];
        float* op = out + ((size_t)(b * SEQ + qt * 64 + tr * 4 + i) << 10)
                        + h * 64 + tc * 4;
        float4 o = {acc[i][0] * linv, acc[i][1] * linv,
                    acc[i][2] * linv, acc[i][3] * linv};
        *(float4*)op = o;
    }
}

extern "C" void kernel_launch(void* const* d_in, const int* in_sizes, int n_in,
                              void* d_out, int out_size, void* d_ws, size_t ws_size,
                              hipStream_t stream) {
    const float* hid  = (const float*)d_in[0];
    const float* mask = (const float*)d_in[1];
    const float* Wq   = (const float*)d_in[2];
    const float* bq   = (const float*)d_in[3];
    const float* Wk   = (const float*)d_in[4];
    const float* bk   = (const float*)d_in[5];
    const float* Wv   = (const float*)d_in[6];
    const float* bv   = (const float*)d_in[7];
    float* out = (float*)d_out;

    // Workspace: q, k, v each [B][NH][S][HD] fp32 = 16.78 MB -> 50.3 MB total
    float* qws = (float*)d_ws;
    float* kws = qws + (size_t)MTOT * HSZ;
    float* vws = kws + (size_t)MTOT * HSZ;

    qkv_proj<<<dim3(24, 32), 256, 0, stream>>>(hid, Wq, bq, Wk, bk, Wv, bv,
                                               qws, kws, vws);
    flash_attn<<<dim3(32, 16, 2), 256, 0, stream>>>(qws, kws, vws, mask, out);
}

// Round 2
// 287.662 us; speedup vs baseline: 2.9848x; 2.9848x over previous
//
#include <hip/hip_runtime.h>
#include <hip/hip_bf16.h>
#include <math.h>

#define HSZ 1024
#define NHD 16
#define SEQ 2048
#define BSZ 2
#define MTOT (BSZ*SEQ)   // 4096

typedef __attribute__((ext_vector_type(4))) float f32x4;
typedef __attribute__((ext_vector_type(8))) __bf16 bf16x8;

__device__ __forceinline__ unsigned short f2bf(float x) {
    union { float f; unsigned u; } v; v.f = x;
    unsigned r = v.u + 0x7FFFu + ((v.u >> 16) & 1u);
    return (unsigned short)(r >> 16);
}

// ---------------------------------------------------------------------------
// fp32 -> bf16 bulk convert (RNE), 8 elems/thread/iter
// ---------------------------------------------------------------------------
__global__ __launch_bounds__(256) void cvt_bf16(
    const float* __restrict__ s, unsigned short* __restrict__ d, int n)
{
    int i = (blockIdx.x * 256 + threadIdx.x) * 8;
    const int stride = gridDim.x * 256 * 8;
    for (; i < n; i += stride) {
        float4 a = *(const float4*)(s + i);
        float4 b = *(const float4*)(s + i + 4);
        uint4 o;
        o.x = f2bf(a.x) | ((unsigned)f2bf(a.y) << 16);
        o.y = f2bf(a.z) | ((unsigned)f2bf(a.w) << 16);
        o.z = f2bf(b.x) | ((unsigned)f2bf(b.y) << 16);
        o.w = f2bf(b.z) | ((unsigned)f2bf(b.w) << 16);
        *(uint4*)(d + i) = o;
    }
}

// ---------------------------------------------------------------------------
// Fused QKV GEMM, bf16 MFMA (m97 structure).
// C[m][n] = sum_k hb[m][k] * W[n][k]  (both K-contiguous row-major)
// Tiles 128x128, BK=32, 256 thr = 4 waves (2x2 of 64x64), 16x16x32 MFMA.
// global_load_lds width 16, st-style XOR swizzle on LDS (both sides).
// Epilogue: +bias, q scaled by 0.125, q/k -> [b][h][s][d], v -> [b][h][d][s].
// ---------------------------------------------------------------------------
__global__ __launch_bounds__(256) void qkv_gemm(
    const unsigned short* __restrict__ hb,
    const unsigned short* __restrict__ wq,
    const unsigned short* __restrict__ wk,
    const unsigned short* __restrict__ wv,
    const float* __restrict__ bq, const float* __restrict__ bk,
    const float* __restrict__ bv,
    unsigned short* __restrict__ qo, unsigned short* __restrict__ ko,
    unsigned short* __restrict__ vo)
{
    __shared__ __align__(16) unsigned short As[128 * 32];  // 8 KB
    __shared__ __align__(16) unsigned short Bs[128 * 32];  // 8 KB

    const int t = threadIdx.x;
    const int w = t >> 6, l = t & 63, g = l >> 4, c = l & 15;
    const int bn = blockIdx.x;            // 24: q 0-7, k 8-15, v 16-23
    const int bm = blockIdx.y;            // 32
    const int which = bn >> 3;
    const int n0 = (bn & 7) << 7;
    const int m0 = bm << 7;
    const unsigned short* W = (which == 0) ? wq : (which == 1) ? wk : wv;
    const float* bb = (which == 0) ? bq : (which == 1) ? bk : bv;
    unsigned short* dst = (which == 0) ? qo : (which == 1) ? ko : vo;
    const float scale = (which == 0) ? 0.125f : 1.0f;
    const int wr = w >> 1, wc = w & 1;

    f32x4 acc[4][4];
    #pragma unroll
    for (int mi = 0; mi < 4; ++mi)
        #pragma unroll
        for (int ni = 0; ni < 4; ++ni) acc[mi][ni] = {0.f, 0.f, 0.f, 0.f};

    for (int k0 = 0; k0 < HSZ; k0 += 32) {
        // stage: 8 chunks of 1024B per tile; wave w does chunks 2w, 2w+1
        #pragma unroll
        for (int i2 = 0; i2 < 2; ++i2) {
            const int chunk = 2 * w + i2;
            const int row = (chunk << 4) + (l >> 2);        // tile row
            const int sg = (l & 3) ^ ((row >> 1) & 3);      // swizzled src granule
            const char* ga = (const char*)hb +
                (((size_t)(m0 + row) << 10) + k0) * 2 + sg * 16;
            const char* gb = (const char*)W +
                (((size_t)(n0 + row) << 10) + k0) * 2 + sg * 16;
            __builtin_amdgcn_global_load_lds(
                (const __attribute__((address_space(1))) unsigned*)ga,
                (__attribute__((address_space(3))) unsigned*)((char*)As + chunk * 1024),
                16, 0, 0);
            __builtin_amdgcn_global_load_lds(
                (const __attribute__((address_space(1))) unsigned*)gb,
                (__attribute__((address_space(3))) unsigned*)((char*)Bs + chunk * 1024),
                16, 0, 0);
        }
        __syncthreads();

        bf16x8 af[4], bfr[4];
        #pragma unroll
        for (int mi = 0; mi < 4; ++mi) {
            const int row = wr * 64 + mi * 16 + c;
            const int gg = g ^ ((row >> 1) & 3);
            af[mi] = *(const bf16x8*)((const char*)As + row * 64 + gg * 16);
        }
        #pragma unroll
        for (int ni = 0; ni < 4; ++ni) {
            const int row = wc * 64 + ni * 16 + c;
            const int gg = g ^ ((row >> 1) & 3);
            bfr[ni] = *(const bf16x8*)((const char*)Bs + row * 64 + gg * 16);
        }
        #pragma unroll
        for (int mi = 0; mi < 4; ++mi)
            #pragma unroll
            for (int ni = 0; ni < 4; ++ni)
                acc[mi][ni] = __builtin_amdgcn_mfma_f32_16x16x32_bf16(
                    af[mi], bfr[ni], acc[mi][ni], 0, 0, 0);
        __syncthreads();
    }

    // epilogue
    #pragma unroll
    for (int ni = 0; ni < 4; ++ni) {
        const int ncol = n0 + wc * 64 + ni * 16 + c;    // 0..1023
        const int hh = ncol >> 6, d = ncol & 63;
        const float bsc = bb[ncol] * scale;
        #pragma unroll
        for (int mi = 0; mi < 4; ++mi) {
            #pragma unroll
            for (int j = 0; j < 4; ++j) {
                const int mrow = m0 + wr * 64 + mi * 16 + g * 4 + j;
                const int bi = mrow >> 11, si = mrow & 2047;
                const float val = acc[mi][ni][j] * scale + bsc;
                if (which < 2)
                    dst[(((size_t)(bi * NHD + hh) * SEQ + si) << 6) + d] = f2bf(val);
                else
                    dst[(((size_t)(bi * NHD + hh) << 6) + d) * SEQ + si] = f2bf(val);
            }
        }
    }
}

// ---------------------------------------------------------------------------
// Flash attention, bf16 MFMA. 256 thr = 4 independent waves (16 q-rows each).
// QK^T and PV via mfma_f32_16x16x32_bf16; online softmax fully in-register
// (row-reduce = shfl_xor within 16-lane groups); P -> padded LDS (per-wave,
// same-wave DS ordering => zero barriers).
// Q,K: [b][h][s][d] bf16;  V: [b][h][d][s] bf16 (pre-transposed by GEMM).
// ---------------------------------------------------------------------------
__global__ __launch_bounds__(256) void attn_mfma(
    const unsigned short* __restrict__ qb, const unsigned short* __restrict__ kb,
    const unsigned short* __restrict__ vb, const float* __restrict__ mask,
    float* __restrict__ out)
{
    __shared__ __align__(16) unsigned short Plds[4][16][72];  // 9.2 KB

    const int t = threadIdx.x;
    const int w = t >> 6, l = t & 63, g = l >> 4, c = l & 15;
    const int qt = blockIdx.x, h = blockIdx.y, b = blockIdx.z;
    const int bh = b * NHD + h;
    const int q0 = qt * 64 + w * 16;

    const unsigned short* qp = qb + ((size_t)bh * SEQ + q0) * 64;
    const unsigned short* kp = kb + (size_t)bh * SEQ * 64;
    const unsigned short* vp = vb + (size_t)bh * 64 * SEQ;
    const float* mp = mask + b * SEQ;

    // Q fragments (hoisted): lane holds Q[q0+c][g*8 + i + 32*ds], pre-scaled
    bf16x8 qf[2];
    qf[0] = *(const bf16x8*)(qp + c * 64 + g * 8);
    qf[1] = *(const bf16x8*)(qp + c * 64 + 32 + g * 8);

    f32x4 o[4];
    float m[4], lsum[4];
    #pragma unroll
    for (int j = 0; j < 4; ++j) {
        o[j] = {0.f, 0.f, 0.f, 0.f};
        m[j] = -INFINITY; lsum[j] = 0.f;
    }

    for (int kt = 0; kt < 32; ++kt) {
        const int kv0 = kt * 64;

        // ---- S = Q K^T : lane holds S[q = g*4+j][kv = c + 16*tt] ----
        f32x4 s[4];
        #pragma unroll
        for (int tt = 0; tt < 4; ++tt) s[tt] = {0.f, 0.f, 0.f, 0.f};
        #pragma unroll
        for (int tt = 0; tt < 4; ++tt) {
            const unsigned short* kr = kp + (size_t)(kv0 + tt * 16 + c) * 64 + g * 8;
            bf16x8 k0f = *(const bf16x8*)kr;
            bf16x8 k1f = *(const bf16x8*)(kr + 32);
            s[tt] = __builtin_amdgcn_mfma_f32_16x16x32_bf16(qf[0], k0f, s[tt], 0, 0, 0);
            s[tt] = __builtin_amdgcn_mfma_f32_16x16x32_bf16(qf[1], k1f, s[tt], 0, 0, 0);
        }

        // additive mask
        #pragma unroll
        for (int tt = 0; tt < 4; ++tt) {
            const float mv = mp[kv0 + tt * 16 + c];
            #pragma unroll
            for (int j = 0; j < 4; ++j) s[tt][j] += mv;
        }

        // ---- online softmax (rows g*4+j, reduce over 16-lane group) ----
        float pm[4];
        #pragma unroll
        for (int j = 0; j < 4; ++j)
            pm[j] = fmaxf(fmaxf(s[0][j], s[1][j]), fmaxf(s[2][j], s[3][j]));
        #pragma unroll
        for (int off = 1; off < 16; off <<= 1)
            #pragma unroll
            for (int j = 0; j < 4; ++j)
                pm[j] = fmaxf(pm[j], __shfl_xor(pm[j], off));

        float corr[4];
        #pragma unroll
        for (int j = 0; j < 4; ++j) {
            const float mn = fmaxf(m[j], pm[j]);
            corr[j] = __expf(m[j] - mn);
            m[j] = mn;
        }
        #pragma unroll
        for (int tt = 0; tt < 4; ++tt)
            #pragma unroll
            for (int j = 0; j < 4; ++j)
                s[tt][j] = __expf(s[tt][j] - m[j]);

        float rs[4];
        #pragma unroll
        for (int j = 0; j < 4; ++j)
            rs[j] = (s[0][j] + s[1][j]) + (s[2][j] + s[3][j]);
        #pragma unroll
        for (int off = 1; off < 16; off <<= 1)
            #pragma unroll
            for (int j = 0; j < 4; ++j)
                rs[j] += __shfl_xor(rs[j], off);
        #pragma unroll
        for (int j = 0; j < 4; ++j)
            lsum[j] = lsum[j] * corr[j] + rs[j];
        #pragma unroll
        for (int tt = 0; tt < 4; ++tt)
            #pragma unroll
            for (int j = 0; j < 4; ++j)
                o[tt][j] *= corr[j];

        // ---- P (bf16) -> per-wave LDS [q=16][kv=64 pad 72] ----
        #pragma unroll
        for (int tt = 0; tt < 4; ++tt)
            #pragma unroll
            for (int j = 0; j < 4; ++j)
                Plds[w][g * 4 + j][c + tt * 16] = f2bf(s[tt][j]);

        // ---- O += P V : A-frag from LDS, B-frag (V^T rows) from global ----
        #pragma unroll
        for (int ks = 0; ks < 2; ++ks) {
            bf16x8 pa = *(const bf16x8*)&Plds[w][c][ks * 32 + g * 8];
            #pragma unroll
            for (int tt = 0; tt < 4; ++tt) {
                bf16x8 vf = *(const bf16x8*)(vp + (size_t)(tt * 16 + c) * SEQ
                                             + kv0 + ks * 32 + g * 8);
                o[tt] = __builtin_amdgcn_mfma_f32_16x16x32_bf16(pa, vf, o[tt], 0, 0, 0);
            }
        }
    }

    // epilogue: /= lsum, write [b][s][h*64+d] fp32
    #pragma unroll
    for (int j = 0; j < 4; ++j) {
        const float linv = 1.f / lsum[j];
        const size_t rowb = ((size_t)(b * SEQ + q0 + g * 4 + j) << 10) + h * 64;
        #pragma unroll
        for (int tt = 0; tt < 4; ++tt)
            out[rowb + c + tt * 16] = o[tt][j] * linv;
    }
}

extern "C" void kernel_launch(void* const* d_in, const int* in_sizes, int n_in,
                              void* d_out, int out_size, void* d_ws, size_t ws_size,
                              hipStream_t stream) {
    const float* hid  = (const float*)d_in[0];
    const float* mask = (const float*)d_in[1];
    const float* Wq   = (const float*)d_in[2];
    const float* bq   = (const float*)d_in[3];
    const float* Wk   = (const float*)d_in[4];
    const float* bk   = (const float*)d_in[5];
    const float* Wv   = (const float*)d_in[6];
    const float* bv   = (const float*)d_in[7];
    float* out = (float*)d_out;

    char* ws = (char*)d_ws;
    unsigned short* qbf = (unsigned short*)(ws);                    // 8 MB
    unsigned short* kbf = (unsigned short*)(ws + 8388608);          // 8 MB
    unsigned short* vbf = (unsigned short*)(ws + 16777216);         // 8 MB ([b][h][d][s])
    unsigned short* hbf = (unsigned short*)(ws + 25165824);         // 8 MB
    unsigned short* wqb = (unsigned short*)(ws + 33554432);         // 2 MB
    unsigned short* wkb = (unsigned short*)(ws + 35651584);         // 2 MB
    unsigned short* wvb = (unsigned short*)(ws + 37748736);         // 2 MB

    cvt_bf16<<<2048, 256, 0, stream>>>(hid, hbf, MTOT * HSZ);
    cvt_bf16<<<512, 256, 0, stream>>>(Wq, wqb, HSZ * HSZ);
    cvt_bf16<<<512, 256, 0, stream>>>(Wk, wkb, HSZ * HSZ);
    cvt_bf16<<<512, 256, 0, stream>>>(Wv, wvb, HSZ * HSZ);

    qkv_gemm<<<dim3(24, 32), 256, 0, stream>>>(hbf, wqb, wkb, wvb,
                                               bq, bk, bv, qbf, kbf, vbf);
    attn_mfma<<<dim3(32, NHD, BSZ), 256, 0, stream>>>(qbf, kbf, vbf, mask, out);
}